// Round 1
// baseline (272.691 us; speedup 1.0000x reference)
//
#include <hip/hip_runtime.h>

// EarlyRewardLoss: N=4096 rows, T=365 timesteps, C=32 classes.
// Wave-per-row: 64 lanes cover T in 6 chunks of 64 (lane-strided, coalesced
// ps / y_true loads). Prefix product of (1-d) via __shfl_up scan + carry.
// pts[t] = d_t * prod_{j<t}(1-d_j), with d_t = ps[t+1] (t<T-1) else 1.0.
// loss = 0.5*mean(sum(-lp*Pt)) - 0.5*mean(sum(Pt*exp(lp)*(1-t/T)))

constexpr int   T_DIM = 365;
constexpr int   C_DIM = 32;
constexpr int   N_DIM = 4096;
constexpr float EPS_OVER_T = 10.0f / 365.0f;

__global__ __launch_bounds__(256, 4)
void early_reward_loss_kernel(const float* __restrict__ logp,  // [N,T,C]
                              const float* __restrict__ ps,    // [N,T]
                              const int*   __restrict__ yt,    // [N,T]
                              float* __restrict__ out)         // [1]
{
    const int lane = threadIdx.x & 63;
    const int wave = threadIdx.x >> 6;
    const int row  = blockIdx.x * 4 + wave;   // grid = N/4 blocks, 4 waves/block

    const float* psr = ps   + (size_t)row * T_DIM;
    const int*   ytr = yt   + (size_t)row * T_DIM;
    const float* lpr = logp + (size_t)row * T_DIM * C_DIM;

    float carry = 1.0f;   // prod of (1-d) over all previous chunks
    float cl = 0.0f;      // sum lp * Pt   (negated at the end)
    float er = 0.0f;      // sum Pt * exp(lp) * (1 - t/T)

    #pragma unroll
    for (int k = 0; k < 6; ++k) {
        const int  t     = k * 64 + lane;
        const bool valid = (t < T_DIM);

        // d_t: ps[t+1] for t<T-1, sentinel 1.0 at t=T-1, 0 for pad lanes
        float d;
        if (t < T_DIM - 1)      d = psr[t + 1];
        else if (t == T_DIM -1) d = 1.0f;
        else                    d = 0.0f;     // m=1: no effect on scan
        const float m = 1.0f - d;

        // inclusive multiplicative scan across the wave
        float s = m;
        #pragma unroll
        for (int off = 1; off < 64; off <<= 1) {
            float o = __shfl_up(s, off);
            if (lane >= off) s *= o;
        }
        // exclusive prefix
        float e = __shfl_up(s, 1);
        if (lane == 0) e = 1.0f;

        const float pt = d * carry * e + EPS_OVER_T;
        carry *= __shfl(s, 63);

        if (valid) {
            const int   y  = ytr[t];
            const float lp = lpr[t * C_DIM + y];       // scattered gather
            cl += lp * pt;
            er += pt * __expf(lp) * (1.0f - (float)t * (1.0f / T_DIM));
        }
    }

    // wave reduction
    #pragma unroll
    for (int off = 32; off > 0; off >>= 1) {
        cl += __shfl_xor(cl, off);
        er += __shfl_xor(er, off);
    }

    __shared__ float part[4];
    if (lane == 0)
        part[wave] = (-0.5f * (cl + er)) * (1.0f / (float)N_DIM);
    __syncthreads();
    if (threadIdx.x == 0) {
        float v = part[0] + part[1] + part[2] + part[3];
        atomicAdd(out, v);
    }
}

extern "C" void kernel_launch(void* const* d_in, const int* in_sizes, int n_in,
                              void* d_out, int out_size, void* d_ws, size_t ws_size,
                              hipStream_t stream) {
    const float* logp = (const float*)d_in[0];
    const float* ps   = (const float*)d_in[1];
    const int*   yt   = (const int*)d_in[2];
    float* out = (float*)d_out;

    // harness re-poisons d_out to 0xAA before every timed launch
    hipMemsetAsync(out, 0, sizeof(float), stream);

    early_reward_loss_kernel<<<N_DIM / 4, 256, 0, stream>>>(logp, ps, yt, out);
}